// Round 1
// baseline (987.268 us; speedup 1.0000x reference)
//
#include <hip/hip_runtime.h>
#include <hip/hip_bf16.h>

// Problem constants
#define NQ 8
#define K  1024
#define D  128
#define BB 16
#define T  2048
#define N  (BB*T)         // 32768 rows
#define BR 64             // rows per block
#define BC 64             // codes per LDS tile
#define NT (K/BC)         // 16 tiles

// d_out layout (floats): z_q (B,D,T) | indices (B,NQ,T) | commit | util
#define ZQ_SIZE   ((size_t)BB*D*T)          // 4194304
#define IDX_SIZE  ((size_t)BB*NQ*T)         // 262144
#define SCALAR_OFF (ZQ_SIZE + IDX_SIZE)     // 4456448

// d_ws layout (floats)
#define WS_PARTIALS 0                 // 512 block commit partials
#define WS_FLAGS    512               // NQ*K usage flags
#define WS_NORMS    (512 + NQ*K)      // NQ*K code norms
#define WS_CLEAR_FLOATS (512 + NQ*K)  // memset region (partials+flags)

__global__ void rvq_norms_kernel(const float* __restrict__ embed,
                                 float* __restrict__ norms) {
    int c = blockIdx.x * blockDim.x + threadIdx.x;  // 0..NQ*K-1
    if (c >= NQ * K) return;
    const float4* e = reinterpret_cast<const float4*>(embed + (size_t)c * D);
    float s = 0.f;
    #pragma unroll 8
    for (int i = 0; i < D / 4; ++i) {
        float4 v = e[i];
        s = fmaf(v.x, v.x, s);
        s = fmaf(v.y, v.y, s);
        s = fmaf(v.z, v.z, s);
        s = fmaf(v.w, v.w, s);
    }
    norms[c] = s;
}

__global__ __launch_bounds__(256, 2)
void rvq_main_kernel(const float* __restrict__ z_e,
                     const float* __restrict__ embed,
                     const float* __restrict__ ws_norms,
                     float* __restrict__ out,
                     float* __restrict__ ws) {
    __shared__ float res_t[D][BR];    // residual, transposed [d][row]
    __shared__ float code_t[D][BC];   // code tile, transposed [d][code]
    __shared__ float red_s[BR][16];
    __shared__ int   red_i[BR][16];
    __shared__ int   row_k[BR];
    __shared__ float cred[256];

    const int tid = threadIdx.x;
    const int blk = blockIdx.x;        // 0..511
    const int b   = blk >> 5;          // 32 blocks per batch element
    const int t0  = (blk & 31) * BR;

    // ---- load initial residual transposed: res_t[d][r] = z_e[b, d, t0+r]
    {
        const int r  = tid & 63;
        const int d0 = tid >> 6;       // 0..3
        for (int d = d0; d < D; d += 4) {
            res_t[d][r] = z_e[((size_t)b * D + d) * T + t0 + r];
        }
    }

    float commit_acc = 0.f;

    const int ty = tid >> 4;           // 0..15 (row group)
    const int tx = tid & 15;           // 0..15 (code group)
    const int r0 = ty * 4;
    const int c0 = tx * 4;

    for (int s = 0; s < NQ; ++s) {
        const float* es = embed + (size_t)s * K * D;
        const float* ns = ws_norms + (size_t)s * K;

        float best[4];
        int   bidx[4];
        #pragma unroll
        for (int i = 0; i < 4; ++i) { best[i] = 3.4e38f; bidx[i] = 0; }

        for (int ct = 0; ct < NT; ++ct) {
            __syncthreads();  // code_t (and res_t on first iter) safe to (re)use
            // ---- stage code tile transposed: code_t[d][cc] = e[ct*BC+cc][d]
            {
                const int cc  = tid >> 2;        // 0..63
                const int dd0 = (tid & 3) * 4;   // 0,4,8,12
                const float* src = es + (size_t)(ct * BC + cc) * D;
                #pragma unroll
                for (int p = 0; p < 8; ++p) {
                    int dd = dd0 + p * 16;
                    float4 v = *reinterpret_cast<const float4*>(src + dd);
                    code_t[dd + 0][cc] = v.x;
                    code_t[dd + 1][cc] = v.y;
                    code_t[dd + 2][cc] = v.z;
                    code_t[dd + 3][cc] = v.w;
                }
            }
            __syncthreads();

            // ---- 4x4 register-tiled dot products over d
            float acc[4][4];
            #pragma unroll
            for (int i = 0; i < 4; ++i)
                #pragma unroll
                for (int j = 0; j < 4; ++j) acc[i][j] = 0.f;

            #pragma unroll 8
            for (int d = 0; d < D; ++d) {
                float4 rv = *reinterpret_cast<const float4*>(&res_t[d][r0]);
                float4 cv = *reinterpret_cast<const float4*>(&code_t[d][c0]);
                float rr[4] = {rv.x, rv.y, rv.z, rv.w};
                float cw[4] = {cv.x, cv.y, cv.z, cv.w};
                #pragma unroll
                for (int i = 0; i < 4; ++i)
                    #pragma unroll
                    for (int j = 0; j < 4; ++j)
                        acc[i][j] = fmaf(rr[i], cw[j], acc[i][j]);
            }

            // ---- scores + running argmin (ascending code order, strict <)
            #pragma unroll
            for (int j = 0; j < 4; ++j) {
                int c = ct * BC + c0 + j;
                float nrm = ns[c];
                #pragma unroll
                for (int i = 0; i < 4; ++i) {
                    float sc = fmaf(-2.f, acc[i][j], nrm);
                    if (sc < best[i]) { best[i] = sc; bidx[i] = c; }
                }
            }
        }

        // ---- block argmin reduce across the 16 code-column threads
        #pragma unroll
        for (int i = 0; i < 4; ++i) {
            red_s[r0 + i][tx] = best[i];
            red_i[r0 + i][tx] = bidx[i];
        }
        __syncthreads();
        if (tid < BR) {
            float bs = red_s[tid][0];
            int   bi = red_i[tid][0];
            #pragma unroll
            for (int x = 1; x < 16; ++x) {
                float s2 = red_s[tid][x];
                int   i2 = red_i[tid][x];
                if (s2 < bs || (s2 == bs && i2 < bi)) { bs = s2; bi = i2; }
            }
            row_k[tid] = bi;
            out[ZQ_SIZE + ((size_t)b * NQ + s) * T + t0 + tid] = (float)bi;
            ws[WS_FLAGS + s * K + bi] = 1.0f;   // benign race, all write 1
        }
        __syncthreads();

        // ---- gather chosen code, update residual in place, accumulate commit
        {
            const int r   = tid & 63;
            const int d0g = (tid >> 6) * 32;   // 0,32,64,96
            const float* ev = es + (size_t)row_k[r] * D;
            #pragma unroll
            for (int p = 0; p < 8; ++p) {
                int d = d0g + p * 4;
                float4 v = *reinterpret_cast<const float4*>(ev + d);
                float e4[4] = {v.x, v.y, v.z, v.w};
                #pragma unroll
                for (int q = 0; q < 4; ++q) {
                    float r_ = res_t[d + q][r];
                    float t_ = e4[q] - r_;        // z_q - r
                    float z_ = r_ + t_;           // z_q_st
                    float nr = r_ - z_;           // new residual
                    res_t[d + q][r] = nr;
                    commit_acc = fmaf(t_, t_, commit_acc);  // (r - z_q)^2
                }
            }
        }
        __syncthreads();
    }

    // ---- write z_q = z_e - final residual (telescoped sum of stage z_q_st)
    {
        const int r  = tid & 63;
        const int d0 = tid >> 6;
        for (int d = d0; d < D; d += 4) {
            size_t gi = ((size_t)b * D + d) * T + t0 + r;
            out[gi] = z_e[gi] - res_t[d][r];
        }
    }

    // ---- deterministic block reduction of commit partials
    cred[tid] = commit_acc;
    __syncthreads();
    for (int o = 128; o > 0; o >>= 1) {
        if (tid < o) cred[tid] += cred[tid + o];
        __syncthreads();
    }
    if (tid == 0) ws[WS_PARTIALS + blk] = cred[0];
}

__global__ void rvq_finalize_kernel(const float* __restrict__ ws,
                                    float* __restrict__ out) {
    __shared__ float sbuf[256];
    const int tid = threadIdx.x;

    // commit: sum 512 block partials
    float cs = 0.f;
    for (int i = tid; i < 512; i += 256) cs += ws[WS_PARTIALS + i];
    sbuf[tid] = cs;
    __syncthreads();
    for (int o = 128; o > 0; o >>= 1) {
        if (tid < o) sbuf[tid] += sbuf[tid + o];
        __syncthreads();
    }
    float commit = sbuf[0] / ((float)NQ * (float)N * (float)D);
    __syncthreads();

    // util: count used codes over all stages
    float fs = 0.f;
    for (int i = tid; i < NQ * K; i += 256)
        fs += (ws[WS_FLAGS + i] != 0.f) ? 1.f : 0.f;
    sbuf[tid] = fs;
    __syncthreads();
    for (int o = 128; o > 0; o >>= 1) {
        if (tid < o) sbuf[tid] += sbuf[tid + o];
        __syncthreads();
    }
    if (tid == 0) {
        out[SCALAR_OFF + 0] = commit;
        out[SCALAR_OFF + 1] = sbuf[0] / (float)(NQ * K);
    }
}

extern "C" void kernel_launch(void* const* d_in, const int* in_sizes, int n_in,
                              void* d_out, int out_size, void* d_ws, size_t ws_size,
                              hipStream_t stream) {
    const float* z_e   = (const float*)d_in[0];
    const float* embed = (const float*)d_in[1];
    float* out = (float*)d_out;
    float* ws  = (float*)d_ws;

    // zero commit partials + usage flags every call (ws is not re-poisoned)
    hipMemsetAsync(d_ws, 0, WS_CLEAR_FLOATS * sizeof(float), stream);

    rvq_norms_kernel<<<(NQ * K + 255) / 256, 256, 0, stream>>>(embed, ws + WS_NORMS);
    rvq_main_kernel<<<512, 256, 0, stream>>>(z_e, embed, ws + WS_NORMS, out, ws);
    rvq_finalize_kernel<<<1, 256, 0, stream>>>(ws, out);
}

// Round 2
// 534.515 us; speedup vs baseline: 1.8470x; 1.8470x over previous
//
#include <hip/hip_runtime.h>
#include <hip/hip_bf16.h>

// Problem constants
#define NQ 8
#define K  1024
#define D  128
#define BB 16
#define T  2048
#define N  (BB*T)          // 32768 rows
#define BR 64              // rows per block
#define NBLK (N/BR)        // 512 blocks

// d_out layout (floats): z_q (B,D,T) | indices (B,NQ,T) | commit | util
#define ZQ_SIZE   ((size_t)BB*D*T)
#define IDX_SIZE  ((size_t)BB*NQ*T)
#define SCALAR_OFF (ZQ_SIZE + IDX_SIZE)

// d_ws layout (floats): partials[512] | flags[NQ*K] | norms[NQ*K] | emb16 (NQ*K*D ushorts)
#define WS_PARTIALS 0
#define WS_FLAGS    512
#define WS_NORMS    (512 + NQ*K)
#define WS_EMB16_F  (WS_NORMS + NQ*K)    // float offset of bf16 codebook
#define WS_REQ_BYTES ((size_t)WS_EMB16_F*4 + (size_t)NQ*K*D*2)

#define EPS  6.0f          // > 2*delta_max (worst-case bf16 dot err ~1.8)
#define CCAP 4096

typedef __attribute__((ext_vector_type(8))) short bf16x8;
typedef __attribute__((ext_vector_type(4))) float f32x4;

__device__ __forceinline__ unsigned short f2bf(float f) {
    unsigned u = __float_as_uint(f);
    u += 0x7FFFu + ((u >> 16) & 1u);   // round-to-nearest-even
    return (unsigned short)(u >> 16);
}

__global__ void rvq_norms_kernel(const float* __restrict__ embed,
                                 float* __restrict__ norms) {
    int c = blockIdx.x * blockDim.x + threadIdx.x;
    if (c >= NQ * K) return;
    const float4* e = reinterpret_cast<const float4*>(embed + (size_t)c * D);
    float s = 0.f;
    #pragma unroll 8
    for (int i = 0; i < D / 4; ++i) {
        float4 v = e[i];
        s = fmaf(v.x, v.x, s);
        s = fmaf(v.y, v.y, s);
        s = fmaf(v.z, v.z, s);
        s = fmaf(v.w, v.w, s);
    }
    norms[c] = s;
}

__global__ void rvq_emb16_kernel(const float* __restrict__ embed,
                                 unsigned short* __restrict__ emb16) {
    int gid = blockIdx.x * blockDim.x + threadIdx.x;   // one per 8 elements
    if (gid >= NQ * K * D / 8) return;
    const float4* src = reinterpret_cast<const float4*>(embed) + (size_t)gid * 2;
    float4 a = src[0], b = src[1];
    bf16x8 o;
    o[0] = (short)f2bf(a.x); o[1] = (short)f2bf(a.y);
    o[2] = (short)f2bf(a.z); o[3] = (short)f2bf(a.w);
    o[4] = (short)f2bf(b.x); o[5] = (short)f2bf(b.y);
    o[6] = (short)f2bf(b.z); o[7] = (short)f2bf(b.w);
    reinterpret_cast<bf16x8*>(emb16)[gid] = o;
}

__global__ __launch_bounds__(256, 2)
void rvq_main_kernel(const float* __restrict__ z_e,
                     const float* __restrict__ embed,
                     const float* __restrict__ ws_norms,
                     const unsigned short* __restrict__ emb16,
                     int use16,
                     float* __restrict__ out,
                     float* __restrict__ ws) {
    __shared__ __align__(16) float res_row[BR][132];   // residual f32, padded rows
    __shared__ __align__(16) float nrm_lds[K];
    __shared__ unsigned int cand[CCAP];
    __shared__ unsigned long long row_best[BR];
    __shared__ int row_k[BR];
    __shared__ float cred[256];
    __shared__ int cand_cnt;

    const int tid  = threadIdx.x;
    const int lane = tid & 63;
    const int wave = tid >> 6;           // 0..3, owns codes [wave*256, wave*256+256)
    const int blk  = blockIdx.x;
    const int b    = blk >> 5;
    const int t0   = (blk & 31) * BR;

    // ---- initial residual: res_row[r][d] = z_e[b, d, t0+r]
    {
        const int r  = tid & 63;
        const int d0 = tid >> 6;
        for (int d = d0; d < D; d += 4)
            res_row[r][d] = z_e[((size_t)b * D + d) * T + t0 + r];
    }

    float commit_acc = 0.f;
    const int lrow  = lane & 15;
    const int lkg   = lane >> 4;         // 0..3 (K-group in MFMA fragment)
    const int wbase = wave * 256;

    for (int s = 0; s < NQ; ++s) {
        const float* es = embed + (size_t)s * K * D;
        __syncthreads();   // prev residual update done; nrm_lds/cand free

        // stage norms (4 KB), init per-stage state
        {
            const float4* np = reinterpret_cast<const float4*>(ws_norms + (size_t)s * K);
            reinterpret_cast<float4*>(nrm_lds)[tid] = np[tid];
        }
        if (tid < BR) row_best[tid] = ~0ULL;
        if (tid == 0) cand_cnt = 0;

        // ---- build A fragments (all 64 rows, K=128 -> 4 frags each) from residual
        bf16x8 afr[4][4];
        #pragma unroll
        for (int rt = 0; rt < 4; ++rt) {
            const float* rp = &res_row[rt * 16 + lrow][lkg * 8];
            #pragma unroll
            for (int kt = 0; kt < 4; ++kt) {
                float4 u = *reinterpret_cast<const float4*>(rp + kt * 32);
                float4 v = *reinterpret_cast<const float4*>(rp + kt * 32 + 4);
                bf16x8 o;
                o[0] = (short)f2bf(u.x); o[1] = (short)f2bf(u.y);
                o[2] = (short)f2bf(u.z); o[3] = (short)f2bf(u.w);
                o[4] = (short)f2bf(v.x); o[5] = (short)f2bf(v.y);
                o[6] = (short)f2bf(v.z); o[7] = (short)f2bf(v.w);
                afr[rt][kt] = o;
            }
        }
        float rm[4][4];
        #pragma unroll
        for (int rt = 0; rt < 4; ++rt)
            #pragma unroll
            for (int j = 0; j < 4; ++j) rm[rt][j] = 3.4e38f;

        __syncthreads();   // nrm_lds + cand_cnt + row_best ready

        const unsigned short* e16s = emb16 + (size_t)s * K * D;

        // ---- bulk scoring: 16 col-tiles of 16 codes, grouped by 2
        #pragma unroll 2
        for (int g = 0; g < 8; ++g) {
            float sc[2][4][4];
            #pragma unroll
            for (int t = 0; t < 2; ++t) {
                const int ct  = g * 2 + t;
                const int col = wbase + ct * 16 + lrow;
                bf16x8 bq[4];
                if (use16) {
                    const bf16x8* bp = reinterpret_cast<const bf16x8*>(
                        e16s + (size_t)col * D + lkg * 8);
                    #pragma unroll
                    for (int kt = 0; kt < 4; ++kt) bq[kt] = bp[kt * 4];
                } else {
                    const float4* fp = reinterpret_cast<const float4*>(
                        es + (size_t)col * D + lkg * 8);
                    #pragma unroll
                    for (int kt = 0; kt < 4; ++kt) {
                        float4 u = fp[kt * 8], v = fp[kt * 8 + 1];
                        bf16x8 o;
                        o[0] = (short)f2bf(u.x); o[1] = (short)f2bf(u.y);
                        o[2] = (short)f2bf(u.z); o[3] = (short)f2bf(u.w);
                        o[4] = (short)f2bf(v.x); o[5] = (short)f2bf(v.y);
                        o[6] = (short)f2bf(v.z); o[7] = (short)f2bf(v.w);
                        bq[kt] = o;
                    }
                }
                f32x4 acc[4];
                #pragma unroll
                for (int rt = 0; rt < 4; ++rt) acc[rt] = (f32x4){0.f, 0.f, 0.f, 0.f};
                #pragma unroll
                for (int kt = 0; kt < 4; ++kt)
                    #pragma unroll
                    for (int rt = 0; rt < 4; ++rt)
                        acc[rt] = __builtin_amdgcn_mfma_f32_16x16x32_bf16(
                            afr[rt][kt], bq[kt], acc[rt], 0, 0, 0);
                const float nrm = nrm_lds[col];
                #pragma unroll
                for (int rt = 0; rt < 4; ++rt)
                    #pragma unroll
                    for (int j = 0; j < 4; ++j)
                        sc[t][rt][j] = fmaf(-2.f, acc[rt][j], nrm);
            }
            // per-row running min (butterfly across the 16 col lanes), then test
            #pragma unroll
            for (int rt = 0; rt < 4; ++rt)
                #pragma unroll
                for (int j = 0; j < 4; ++j) {
                    float m2 = fminf(sc[0][rt][j], sc[1][rt][j]);
                    m2 = fminf(m2, __shfl_xor(m2, 1, 16));
                    m2 = fminf(m2, __shfl_xor(m2, 2, 16));
                    m2 = fminf(m2, __shfl_xor(m2, 4, 16));
                    m2 = fminf(m2, __shfl_xor(m2, 8, 16));
                    rm[rt][j] = fminf(rm[rt][j], m2);
                }
            #pragma unroll
            for (int t = 0; t < 2; ++t)
                #pragma unroll
                for (int rt = 0; rt < 4; ++rt)
                    #pragma unroll
                    for (int j = 0; j < 4; ++j)
                        if (sc[t][rt][j] <= rm[rt][j] + EPS) {
                            int row = rt * 16 + lkg * 4 + j;
                            int col = wbase + (g * 2 + t) * 16 + lrow;
                            int pos = atomicAdd(&cand_cnt, 1);
                            if (pos < CCAP) cand[pos] = (unsigned)((row << 10) | col);
                        }
        }
        __syncthreads();   // all candidates pushed

        // ---- exact f32 rescore of candidates; lexicographic (dist, idx) min
        int nc = cand_cnt; if (nc > CCAP) nc = CCAP;
        for (int i = tid; i < nc; i += 256) {
            unsigned e = cand[i];
            int row = (int)(e >> 10), col = (int)(e & (K - 1));
            const float*  rp = &res_row[row][0];
            const float4* ep = reinterpret_cast<const float4*>(es + (size_t)col * D);
            float dot = 0.f;
            #pragma unroll 8
            for (int q = 0; q < 32; ++q) {
                float4 rv = *reinterpret_cast<const float4*>(rp + q * 4);
                float4 evv = ep[q];
                dot = fmaf(rv.x, evv.x, dot);
                dot = fmaf(rv.y, evv.y, dot);
                dot = fmaf(rv.z, evv.z, dot);
                dot = fmaf(rv.w, evv.w, dot);
            }
            float dist = fmaf(-2.f, dot, nrm_lds[col]);
            unsigned du = __float_as_uint(dist);
            du ^= (du >> 31) ? 0xFFFFFFFFu : 0x80000000u;   // order-preserving map
            unsigned long long key = ((unsigned long long)du << 32) | (unsigned)col;
            atomicMin(&row_best[row], key);
        }
        __syncthreads();

        if (tid < BR) {
            int idx = (int)(row_best[tid] & (unsigned)(K - 1));
            row_k[tid] = idx;
            out[ZQ_SIZE + ((size_t)b * NQ + s) * T + t0 + tid] = (float)idx;
            ws[WS_FLAGS + s * K + idx] = 1.0f;   // benign race, all write 1
        }
        __syncthreads();

        // ---- residual update (mirrors reference f32 op order) + commit
        {
            const int row = tid >> 2;
            const int d0  = (tid & 3) * 32;
            const float* ev = es + (size_t)row_k[row] * D + d0;
            float* rr = &res_row[row][d0];
            #pragma unroll
            for (int p = 0; p < 8; ++p) {
                float4 e4 = *reinterpret_cast<const float4*>(ev + p * 4);
                float4 r4 = *reinterpret_cast<float4*>(rr + p * 4);
                float tx = e4.x - r4.x, zx = r4.x + tx;
                float ty = e4.y - r4.y, zy = r4.y + ty;
                float tz = e4.z - r4.z, zz = r4.z + tz;
                float tw = e4.w - r4.w, zw = r4.w + tw;
                float4 nr;
                nr.x = r4.x - zx; nr.y = r4.y - zy; nr.z = r4.z - zz; nr.w = r4.w - zw;
                commit_acc = fmaf(tx, tx, commit_acc);
                commit_acc = fmaf(ty, ty, commit_acc);
                commit_acc = fmaf(tz, tz, commit_acc);
                commit_acc = fmaf(tw, tw, commit_acc);
                *reinterpret_cast<float4*>(rr + p * 4) = nr;
            }
        }
    }
    __syncthreads();

    // ---- z_q = z_e - final residual (telescoped sum of stage z_q_st)
    {
        const int r  = tid & 63;
        const int d0 = tid >> 6;
        for (int d = d0; d < D; d += 4) {
            size_t gi = ((size_t)b * D + d) * T + t0 + r;
            out[gi] = z_e[gi] - res_row[r][d];
        }
    }

    // ---- deterministic block reduction of commit partials
    cred[tid] = commit_acc;
    __syncthreads();
    for (int o = 128; o > 0; o >>= 1) {
        if (tid < o) cred[tid] += cred[tid + o];
        __syncthreads();
    }
    if (tid == 0) ws[WS_PARTIALS + blk] = cred[0];
}

__global__ void rvq_finalize_kernel(const float* __restrict__ ws,
                                    float* __restrict__ out) {
    __shared__ float sbuf[256];
    const int tid = threadIdx.x;

    float cs = 0.f;
    for (int i = tid; i < NBLK; i += 256) cs += ws[WS_PARTIALS + i];
    sbuf[tid] = cs;
    __syncthreads();
    for (int o = 128; o > 0; o >>= 1) {
        if (tid < o) sbuf[tid] += sbuf[tid + o];
        __syncthreads();
    }
    float commit = sbuf[0] / ((float)NQ * (float)N * (float)D);
    __syncthreads();

    float fs = 0.f;
    for (int i = tid; i < NQ * K; i += 256)
        fs += (ws[WS_FLAGS + i] != 0.f) ? 1.f : 0.f;
    sbuf[tid] = fs;
    __syncthreads();
    for (int o = 128; o > 0; o >>= 1) {
        if (tid < o) sbuf[tid] += sbuf[tid + o];
        __syncthreads();
    }
    if (tid == 0) {
        out[SCALAR_OFF + 0] = commit;
        out[SCALAR_OFF + 1] = sbuf[0] / (float)(NQ * K);
    }
}

extern "C" void kernel_launch(void* const* d_in, const int* in_sizes, int n_in,
                              void* d_out, int out_size, void* d_ws, size_t ws_size,
                              hipStream_t stream) {
    const float* z_e   = (const float*)d_in[0];
    const float* embed = (const float*)d_in[1];
    float* out = (float*)d_out;
    float* ws  = (float*)d_ws;

    int use16 = (ws_size >= WS_REQ_BYTES) ? 1 : 0;

    hipMemsetAsync(d_ws, 0, (512 + NQ * K) * sizeof(float), stream);
    rvq_norms_kernel<<<(NQ * K + 255) / 256, 256, 0, stream>>>(embed, ws + WS_NORMS);
    if (use16)
        rvq_emb16_kernel<<<(NQ * K * D / 8 + 255) / 256, 256, 0, stream>>>(
            embed, (unsigned short*)(ws + WS_EMB16_F));
    rvq_main_kernel<<<NBLK, 256, 0, stream>>>(
        z_e, embed, ws + WS_NORMS, (const unsigned short*)(ws + WS_EMB16_F),
        use16, out, ws);
    rvq_finalize_kernel<<<1, 256, 0, stream>>>(ws, out);
}

// Round 3
// 338.250 us; speedup vs baseline: 2.9187x; 1.5802x over previous
//
#include <hip/hip_runtime.h>
#include <hip/hip_bf16.h>

// Problem constants
#define NQ 8
#define K  1024
#define D  128
#define BB 16
#define T  2048
#define N  (BB*T)          // 32768 rows
#define BR 64              // rows per block
#define NBLK (N/BR)        // 512 blocks

// d_out layout (floats): z_q (B,D,T) | indices (B,NQ,T) | commit | util
#define ZQ_SIZE   ((size_t)BB*D*T)
#define IDX_SIZE  ((size_t)BB*NQ*T)
#define SCALAR_OFF (ZQ_SIZE + IDX_SIZE)

// d_ws layout (floats): partials[512] | flags[NQ*K] | norms[NQ*K] | emb16 (NQ*K*D ushorts)
#define WS_PARTIALS 0
#define WS_FLAGS    512
#define WS_NORMS    (512 + NQ*K)
#define WS_EMB16_F  (WS_NORMS + NQ*K)
#define WS_REQ_BYTES ((size_t)WS_EMB16_F*4 + (size_t)NQ*K*D*2)

#define EPS  6.0f          // > 2*delta_max of bf16 screen (worst-case ~1.4)
#define CCAP 768

typedef __attribute__((ext_vector_type(8))) short bf16x8;
typedef __attribute__((ext_vector_type(4))) float f32x4;
typedef __attribute__((ext_vector_type(4))) unsigned int u32x4;

__device__ __forceinline__ unsigned short f2bf(float f) {
    unsigned u = __float_as_uint(f);
    u += 0x7FFFu + ((u >> 16) & 1u);   // round-to-nearest-even
    return (unsigned short)(u >> 16);
}

__device__ __forceinline__ unsigned cvt_pk_bf16(float lo, float hi) {
    unsigned r;
    asm("v_cvt_pk_bf16_f32 %0, %1, %2" : "=v"(r) : "v"(lo), "v"(hi));
    return r;   // low16 = bf16(lo), high16 = bf16(hi)
}

__global__ void rvq_norms_kernel(const float* __restrict__ embed,
                                 float* __restrict__ norms) {
    int c = blockIdx.x * blockDim.x + threadIdx.x;
    if (c >= NQ * K) return;
    const float4* e = reinterpret_cast<const float4*>(embed + (size_t)c * D);
    float s = 0.f;
    #pragma unroll 8
    for (int i = 0; i < D / 4; ++i) {
        float4 v = e[i];
        s = fmaf(v.x, v.x, s);
        s = fmaf(v.y, v.y, s);
        s = fmaf(v.z, v.z, s);
        s = fmaf(v.w, v.w, s);
    }
    norms[c] = s;
}

__global__ void rvq_emb16_kernel(const float* __restrict__ embed,
                                 unsigned short* __restrict__ emb16) {
    int gid = blockIdx.x * blockDim.x + threadIdx.x;   // one per 8 elements
    if (gid >= NQ * K * D / 8) return;
    const float4* src = reinterpret_cast<const float4*>(embed) + (size_t)gid * 2;
    float4 a = src[0], b = src[1];
    bf16x8 o;
    o[0] = (short)f2bf(a.x); o[1] = (short)f2bf(a.y);
    o[2] = (short)f2bf(a.z); o[3] = (short)f2bf(a.w);
    o[4] = (short)f2bf(b.x); o[5] = (short)f2bf(b.y);
    o[6] = (short)f2bf(b.z); o[7] = (short)f2bf(b.w);
    reinterpret_cast<bf16x8*>(emb16)[gid] = o;
}

// One sweep over this wave's 256 codes. PUSH=0: accumulate per-slot min into
// rmth. PUSH=1: rmth holds thresholds; push candidates within threshold.
template<int PUSH>
__device__ __forceinline__ void rvq_score_pass(
    const bf16x8 (&afr)[4][4], const float (&nrm_reg)[16], float (&rmth)[16],
    const unsigned short* __restrict__ e16s, const float* __restrict__ es,
    int use16, int wbase, int lrow, int lkg,
    unsigned int* cand, int* cand_cnt)
{
    #pragma unroll 2
    for (int ct = 0; ct < 16; ++ct) {
        const int col = wbase + ct * 16 + lrow;
        bf16x8 bq[4];
        if (use16) {
            const bf16x8* bp = reinterpret_cast<const bf16x8*>(
                e16s + (size_t)col * D + lkg * 8);
            #pragma unroll
            for (int kt = 0; kt < 4; ++kt) bq[kt] = bp[kt * 4];
        } else {
            const float4* fp = reinterpret_cast<const float4*>(
                es + (size_t)col * D + lkg * 8);
            #pragma unroll
            for (int kt = 0; kt < 4; ++kt) {
                float4 u = fp[kt * 8], v = fp[kt * 8 + 1];
                u32x4 w;
                w[0] = cvt_pk_bf16(u.x, u.y); w[1] = cvt_pk_bf16(u.z, u.w);
                w[2] = cvt_pk_bf16(v.x, v.y); w[3] = cvt_pk_bf16(v.z, v.w);
                bq[kt] = __builtin_bit_cast(bf16x8, w);
            }
        }
        f32x4 acc[4];
        #pragma unroll
        for (int rt = 0; rt < 4; ++rt) acc[rt] = (f32x4){0.f, 0.f, 0.f, 0.f};
        #pragma unroll
        for (int kt = 0; kt < 4; ++kt)
            #pragma unroll
            for (int rt = 0; rt < 4; ++rt)
                acc[rt] = __builtin_amdgcn_mfma_f32_16x16x32_bf16(
                    afr[rt][kt], bq[kt], acc[rt], 0, 0, 0);
        const float nrm = nrm_reg[ct];
        #pragma unroll
        for (int rt = 0; rt < 4; ++rt)
            #pragma unroll
            for (int j = 0; j < 4; ++j) {
                float sc = fmaf(-2.f, acc[rt][j], nrm);
                if (PUSH) {
                    if (sc <= rmth[rt * 4 + j]) {
                        int row = rt * 16 + lkg * 4 + j;
                        int pos = atomicAdd(cand_cnt, 1);
                        if (pos < CCAP) cand[pos] = (unsigned)((row << 10) | col);
                    }
                } else {
                    rmth[rt * 4 + j] = fminf(rmth[rt * 4 + j], sc);
                }
            }
    }
}

__global__ __launch_bounds__(256, 3)
void rvq_main_kernel(const float* __restrict__ z_e,
                     const float* __restrict__ embed,
                     const float* __restrict__ ws_norms,
                     const unsigned short* __restrict__ emb16,
                     int use16,
                     float* __restrict__ out,
                     float* __restrict__ ws) {
    __shared__ __align__(16) float res_row[BR][132];   // residual f32, padded rows
    __shared__ unsigned int cand[CCAP];
    __shared__ float row_minw[4][BR];
    __shared__ unsigned long long row_best[BR];
    __shared__ float cred[256];
    __shared__ int cand_cnt;

    const int tid  = threadIdx.x;
    const int lane = tid & 63;
    const int wave = tid >> 6;           // owns codes [wave*256, wave*256+256)
    const int blk  = blockIdx.x;
    const int b    = blk >> 5;
    const int t0   = (blk & 31) * BR;

    // ---- initial residual: res_row[r][d] = z_e[b, d, t0+r] (coalesced in r)
    {
        const int r  = tid & 63;
        const int d0 = tid >> 6;
        for (int d = d0; d < D; d += 4)
            res_row[r][d] = z_e[((size_t)b * D + d) * T + t0 + r];
    }
    __syncthreads();

    float commit_acc = 0.f;
    const int lrow  = lane & 15;
    const int lkg   = lane >> 4;
    const int wbase = wave * 256;

    for (int s = 0; s < NQ; ++s) {
        const float* es = embed + (size_t)s * K * D;
        const float* ns = ws_norms + (size_t)s * K;
        const unsigned short* e16s = emb16 + (size_t)s * K * D;

        // per-stage resets (epoch: before barrier (1); used after (1)/(2))
        if (tid < BR) row_best[tid] = ~0ULL;
        if (tid == 0) cand_cnt = 0;

        // stage norms for this thread's 16 columns
        float nrm_reg[16];
        #pragma unroll
        for (int ct = 0; ct < 16; ++ct) nrm_reg[ct] = ns[wbase + ct * 16 + lrow];

        // ---- A fragments from residual (packed bf16 convert)
        bf16x8 afr[4][4];
        #pragma unroll
        for (int rt = 0; rt < 4; ++rt) {
            const float* rp = &res_row[rt * 16 + lrow][lkg * 8];
            #pragma unroll
            for (int kt = 0; kt < 4; ++kt) {
                float4 u = *reinterpret_cast<const float4*>(rp + kt * 32);
                float4 v = *reinterpret_cast<const float4*>(rp + kt * 32 + 4);
                u32x4 w;
                w[0] = cvt_pk_bf16(u.x, u.y); w[1] = cvt_pk_bf16(u.z, u.w);
                w[2] = cvt_pk_bf16(v.x, v.y); w[3] = cvt_pk_bf16(v.z, v.w);
                afr[rt][kt] = __builtin_bit_cast(bf16x8, w);
            }
        }

        float rmth[16];
        #pragma unroll
        for (int i = 0; i < 16; ++i) rmth[i] = 3.4e38f;

        // ---- pass 1: per-slot min only
        rvq_score_pass<0>(afr, nrm_reg, rmth, e16s, es, use16,
                          wbase, lrow, lkg, cand, &cand_cnt);

        // one butterfly at the end (16 col lanes -> wave row min)
        #pragma unroll
        for (int i = 0; i < 16; ++i) {
            float m = rmth[i];
            m = fminf(m, __shfl_xor(m, 1, 16));
            m = fminf(m, __shfl_xor(m, 2, 16));
            m = fminf(m, __shfl_xor(m, 4, 16));
            m = fminf(m, __shfl_xor(m, 8, 16));
            rmth[i] = m;
        }
        if (lrow == 0) {
            #pragma unroll
            for (int i = 0; i < 16; ++i)
                row_minw[wave][(i >> 2) * 16 + lkg * 4 + (i & 3)] = rmth[i];
        }
        __syncthreads();   // (1) row_minw + resets visible

        // thresholds = global row min over 4 waves + EPS
        #pragma unroll
        for (int i = 0; i < 16; ++i) {
            int row = (i >> 2) * 16 + lkg * 4 + (i & 3);
            float m = fminf(fminf(row_minw[0][row], row_minw[1][row]),
                            fminf(row_minw[2][row], row_minw[3][row]));
            rmth[i] = m + EPS;
        }

        // ---- pass 2: recompute scores, push rare candidates
        rvq_score_pass<1>(afr, nrm_reg, rmth, e16s, es, use16,
                          wbase, lrow, lkg, cand, &cand_cnt);
        __syncthreads();   // (2) cand ready

        // ---- exact f32 rescore; lexicographic (dist, idx) min
        int nc = cand_cnt; if (nc > CCAP) nc = CCAP;
        for (int i = tid; i < nc; i += 256) {
            unsigned e = cand[i];
            int row = (int)(e >> 10), col = (int)(e & (K - 1));
            const float*  rp = &res_row[row][0];
            const float4* ep = reinterpret_cast<const float4*>(es + (size_t)col * D);
            float dot = 0.f;
            #pragma unroll 8
            for (int q = 0; q < 32; ++q) {
                float4 rv = *reinterpret_cast<const float4*>(rp + q * 4);
                float4 evv = ep[q];
                dot = fmaf(rv.x, evv.x, dot);
                dot = fmaf(rv.y, evv.y, dot);
                dot = fmaf(rv.z, evv.z, dot);
                dot = fmaf(rv.w, evv.w, dot);
            }
            float dist = fmaf(-2.f, dot, ns[col]);
            unsigned du = __float_as_uint(dist);
            du ^= (du >> 31) ? 0xFFFFFFFFu : 0x80000000u;
            unsigned long long key = ((unsigned long long)du << 32) | (unsigned)col;
            atomicMin(&row_best[row], key);
        }
        __syncthreads();   // (3) row_best final

        // ---- index out + flags + residual update (reads row_best directly)
        if (tid < BR) {
            int idx = (int)(row_best[tid] & (unsigned)(K - 1));
            out[ZQ_SIZE + ((size_t)b * NQ + s) * T + t0 + tid] = (float)idx;
            ws[WS_FLAGS + s * K + idx] = 1.0f;   // benign race
        }
        {
            const int row = tid >> 2;
            const int d0  = (tid & 3) * 32;
            const int idx = (int)(row_best[row] & (unsigned)(K - 1));
            const float* ev = es + (size_t)idx * D + d0;
            float* rr = &res_row[row][d0];
            #pragma unroll
            for (int p = 0; p < 8; ++p) {
                float4 e4 = *reinterpret_cast<const float4*>(ev + p * 4);
                float4 r4 = *reinterpret_cast<float4*>(rr + p * 4);
                float tx = e4.x - r4.x, zx = r4.x + tx;
                float ty = e4.y - r4.y, zy = r4.y + ty;
                float tz = e4.z - r4.z, zz = r4.z + tz;
                float tw = e4.w - r4.w, zw = r4.w + tw;
                float4 nr;
                nr.x = r4.x - zx; nr.y = r4.y - zy; nr.z = r4.z - zz; nr.w = r4.w - zw;
                commit_acc = fmaf(tx, tx, commit_acc);
                commit_acc = fmaf(ty, ty, commit_acc);
                commit_acc = fmaf(tz, tz, commit_acc);
                commit_acc = fmaf(tw, tw, commit_acc);
                *reinterpret_cast<float4*>(rr + p * 4) = nr;
            }
        }
        __syncthreads();   // (4) res_row stable, row_best reads done
    }

    // ---- z_q = z_e - final residual (telescoped sum of stage z_q_st)
    {
        const int r  = tid & 63;
        const int d0 = tid >> 6;
        for (int d = d0; d < D; d += 4) {
            size_t gi = ((size_t)b * D + d) * T + t0 + r;
            out[gi] = z_e[gi] - res_row[r][d];
        }
    }

    // ---- deterministic block reduction of commit partials
    cred[tid] = commit_acc;
    __syncthreads();
    for (int o = 128; o > 0; o >>= 1) {
        if (tid < o) cred[tid] += cred[tid + o];
        __syncthreads();
    }
    if (tid == 0) ws[WS_PARTIALS + blk] = cred[0];
}

__global__ void rvq_finalize_kernel(const float* __restrict__ ws,
                                    float* __restrict__ out) {
    __shared__ float sbuf[256];
    const int tid = threadIdx.x;

    float cs = 0.f;
    for (int i = tid; i < NBLK; i += 256) cs += ws[WS_PARTIALS + i];
    sbuf[tid] = cs;
    __syncthreads();
    for (int o = 128; o > 0; o >>= 1) {
        if (tid < o) sbuf[tid] += sbuf[tid + o];
        __syncthreads();
    }
    float commit = sbuf[0] / ((float)NQ * (float)N * (float)D);
    __syncthreads();

    float fs = 0.f;
    for (int i = tid; i < NQ * K; i += 256)
        fs += (ws[WS_FLAGS + i] != 0.f) ? 1.f : 0.f;
    sbuf[tid] = fs;
    __syncthreads();
    for (int o = 128; o > 0; o >>= 1) {
        if (tid < o) sbuf[tid] += sbuf[tid + o];
        __syncthreads();
    }
    if (tid == 0) {
        out[SCALAR_OFF + 0] = commit;
        out[SCALAR_OFF + 1] = sbuf[0] / (float)(NQ * K);
    }
}

extern "C" void kernel_launch(void* const* d_in, const int* in_sizes, int n_in,
                              void* d_out, int out_size, void* d_ws, size_t ws_size,
                              hipStream_t stream) {
    const float* z_e   = (const float*)d_in[0];
    const float* embed = (const float*)d_in[1];
    float* out = (float*)d_out;
    float* ws  = (float*)d_ws;

    int use16 = (ws_size >= WS_REQ_BYTES) ? 1 : 0;

    hipMemsetAsync(d_ws, 0, (512 + NQ * K) * sizeof(float), stream);
    rvq_norms_kernel<<<(NQ * K + 255) / 256, 256, 0, stream>>>(embed, ws + WS_NORMS);
    if (use16)
        rvq_emb16_kernel<<<(NQ * K * D / 8 + 255) / 256, 256, 0, stream>>>(
            embed, (unsigned short*)(ws + WS_EMB16_F));
    rvq_main_kernel<<<NBLK, 256, 0, stream>>>(
        z_e, embed, ws + WS_NORMS, (const unsigned short*)(ws + WS_EMB16_F),
        use16, out, ws);
    rvq_finalize_kernel<<<1, 256, 0, stream>>>(ws, out);
}